// Round 1
// baseline (2791.903 us; speedup 1.0000x reference)
//
#include <hip/hip_runtime.h>
#include <hip/hip_bf16.h>

typedef __bf16 bf16x8 __attribute__((ext_vector_type(8)));
typedef float  f32x4  __attribute__((ext_vector_type(4)));

#define GPTR(p) ((const __attribute__((address_space(1))) void*)(p))
#define LPTR(p) ((__attribute__((address_space(3))) void*)(p))

// ---------------- elementwise f32 -> bf16 ----------------
__global__ void cvt_f32_bf16_kernel(const float* __restrict__ in, __bf16* __restrict__ out, long n) {
  long i = ((long)blockIdx.x * blockDim.x + threadIdx.x) * 4;
  if (i + 3 < n) {
    float4 v = *(const float4*)(in + i);
    out[i]   = (__bf16)v.x; out[i+1] = (__bf16)v.y;
    out[i+2] = (__bf16)v.z; out[i+3] = (__bf16)v.w;
  } else {
    for (long j = i; j < n; ++j) out[j] = (__bf16)in[j];
  }
}

// ---------------- transpose + cvt: src [R][C] f32 -> dst [Cpad][R] bf16 (pad rows zeroed) ----------------
__global__ void transpose_cvt_kernel(const float* __restrict__ src, __bf16* __restrict__ dst,
                                     int R, int C, int Cpad, long srcStride, long dstStride) {
  __shared__ float tile[32][33];
  const float* s = src + (long)blockIdx.z * srcStride;
  __bf16* d = dst + (long)blockIdx.z * dstStride;
  int r0 = blockIdx.x * 32, c0 = blockIdx.y * 32;
  int tx = threadIdx.x, ty = threadIdx.y;
  #pragma unroll
  for (int i = ty; i < 32; i += 8) {
    int r = r0 + i, c = c0 + tx;
    tile[i][tx] = (r < R && c < C) ? s[(long)r * C + c] : 0.0f;
  }
  __syncthreads();
  #pragma unroll
  for (int i = ty; i < 32; i += 8) {
    int oc = c0 + i;    // dst row (= src col, padded)
    int orr = r0 + tx;  // dst col (= src row)
    if (oc < Cpad) d[(long)oc * R + orr] = (__bf16)tile[tx][i];
  }
}

// ---------------- bf16 MFMA GEMM: C = [relu](A @ B^T^T + bias) ----------------
// A [Mrows][K] bf16, BT [N][K] bf16, bias f32 [biasN], Cout [Mrows][N] bf16.
// 128x128 tile, BK=32, 256 threads (4 waves, 2x2), m97-style global_load_lds staging.
template<int RELU>
__global__ __launch_bounds__(256)
void gemm_bt(const __bf16* __restrict__ A, const __bf16* __restrict__ BT,
             const float* __restrict__ bias, __bf16* __restrict__ Cout,
             int Mrows, int N, int K, int biasN,
             long strideA, long strideBT, long strideBias, long strideC)
{
  const int z = blockIdx.z;
  A    += (long)z * strideA;
  BT   += (long)z * strideBT;
  bias += (long)z * strideBias;
  Cout += (long)z * strideC;

  __shared__ __bf16 lds_a[128 * 32];
  __shared__ __bf16 lds_b[128 * 32];

  const int tid  = threadIdx.x;
  const int lane = tid & 63;
  const int wave = tid >> 6;   // 0..3
  const int wr = wave >> 1;    // 0..1
  const int wc = wave & 1;     // 0..1
  const int l15 = lane & 15;
  const int l4  = lane >> 4;

  const int brow = blockIdx.x * 128;
  const int bcol = blockIdx.y * 128;

  f32x4 acc[4][4] = {};

  // staging geometry: per wave-issue, 64 lanes x 16B = 1024B = 16 rows x 32 cols (bf16)
  const int srow = lane >> 2;        // 0..15 (row within 16-row chunk)
  const int scol = (lane & 3) * 8;   // 0,8,16,24

  for (int k0 = 0; k0 < K; k0 += 32) {
    #pragma unroll
    for (int i = 0; i < 2; ++i) {
      int chunk = wave + 4 * i;              // 0..7 -> rows [16*chunk, 16*chunk+16)
      int rr = 16 * chunk + srow;
      const __bf16* ga = A + (long)(brow + rr) * K + k0 + scol;
      __builtin_amdgcn_global_load_lds(GPTR(ga), LPTR(&lds_a[(16 * chunk) * 32]), 16, 0, 0);
      const __bf16* gb = BT + (long)(bcol + rr) * K + k0 + scol;
      __builtin_amdgcn_global_load_lds(GPTR(gb), LPTR(&lds_b[(16 * chunk) * 32]), 16, 0, 0);
    }
    __syncthreads();

    bf16x8 af[4], bfr[4];
    #pragma unroll
    for (int i = 0; i < 4; ++i) {
      af[i]  = *(const bf16x8*)&lds_a[(wr * 64 + i * 16 + l15) * 32 + l4 * 8];
      bfr[i] = *(const bf16x8*)&lds_b[(wc * 64 + i * 16 + l15) * 32 + l4 * 8];
    }
    #pragma unroll
    for (int mi = 0; mi < 4; ++mi)
      #pragma unroll
      for (int ni = 0; ni < 4; ++ni)
        acc[mi][ni] = __builtin_amdgcn_mfma_f32_16x16x32_bf16(af[mi], bfr[ni], acc[mi][ni], 0, 0, 0);
    __syncthreads();
  }

  // epilogue: C/D layout col=lane&15, row=(lane>>4)*4+j
  #pragma unroll
  for (int ni = 0; ni < 4; ++ni) {
    int gc = bcol + wc * 64 + ni * 16 + l15;
    float bv = (gc < biasN) ? bias[gc] : 0.0f;
    #pragma unroll
    for (int mi = 0; mi < 4; ++mi) {
      #pragma unroll
      for (int j = 0; j < 4; ++j) {
        int gr = brow + wr * 64 + mi * 16 + l4 * 4 + j;
        float v = acc[mi][ni][j] + bv;
        if (RELU) v = v > 0.0f ? v : 0.0f;
        Cout[(long)gr * N + gc] = (__bf16)v;
      }
    }
  }
}

// ---------------- delegation logits + softmax: Dmat[b][m][n] ----------------
__global__ __launch_bounds__(64)
void delegation_kernel(const __bf16* __restrict__ h2,   // [16][B][2048]
                       const float* __restrict__ Wd,    // [16][2048][16]
                       const float* __restrict__ bd,    // [16][16]
                       float* __restrict__ Dmat,        // [B][16][16]
                       int B)
{
  const int b = blockIdx.x, m = blockIdx.y;
  const int lane = threadIdx.x;
  const __bf16* h = h2 + ((long)m * B + b) * 2048;
  const float* w = Wd + (long)m * 2048 * 16;

  float part[16];
  #pragma unroll
  for (int n = 0; n < 16; ++n) part[n] = 0.0f;
  for (int k = lane; k < 2048; k += 64) {
    float hv = (float)h[k];
    const float* wrow = w + (long)k * 16;
    #pragma unroll
    for (int n = 0; n < 16; ++n) part[n] += hv * wrow[n];
  }
  __shared__ float red[64][17];
  #pragma unroll
  for (int n = 0; n < 16; ++n) red[lane][n] = part[n];
  __syncthreads();
  __shared__ float dlv[16], ev[16];
  if (lane < 16) {
    float s = 0.0f;
    for (int i = 0; i < 64; ++i) s += red[i][lane];
    s += bd[m * 16 + lane];
    dlv[lane] = s;
  }
  __syncthreads();
  if (lane < 16) {
    float mx = dlv[0];
    #pragma unroll
    for (int i = 1; i < 16; ++i) mx = fmaxf(mx, dlv[i]);
    ev[lane] = __expf(dlv[lane] - mx);
  }
  __syncthreads();
  if (lane < 16) {
    float s = 0.0f;
    #pragma unroll
    for (int i = 0; i < 16; ++i) s += ev[i];
    Dmat[((long)b * 16 + m) * 16 + lane] = ev[lane] / s;
  }
}

// ---------------- power iteration (10 steps) -> power (output) + log p ----------------
__global__ __launch_bounds__(256)
void power_kernel(const float* __restrict__ Dmat,  // [B][16][16]
                  float* __restrict__ power_out,   // [B][16] (into d_out)
                  float* __restrict__ logp,        // [B][16]
                  int B)
{
  const int wv = threadIdx.x >> 6, lane = threadIdx.x & 63;
  const int b = blockIdx.x * 4 + wv;
  const int n = lane & 15;
  const float* D = Dmat + (long)b * 256;
  float p = 1.0f / 16.0f;
  for (int it = 0; it < 10; ++it) {
    float np_ = 0.0f;
    #pragma unroll
    for (int m = 0; m < 16; ++m) {
      float pm = __shfl(p, m, 16);
      np_ += pm * D[m * 16 + n];
    }
    float s = np_;
    #pragma unroll
    for (int o = 8; o >= 1; o >>= 1) s += __shfl_xor(s, o, 16);
    p = np_ / s;
  }
  if (lane < 16) {
    power_out[(long)b * 16 + n] = p;
    logp[(long)b * 16 + n] = logf(p + 1e-9f);
  }
}

// ---------------- per-(m,b) row stats of ys -> off[b][m] = logp - max - lse ----------------
__global__ __launch_bounds__(256)
void rowstats_kernel(const __bf16* __restrict__ ys,  // [16][B][1024], valid c<1000
                     const float* __restrict__ logp, // [B][16]
                     float* __restrict__ offv,       // [B][16]
                     int B)
{
  const int wv = threadIdx.x >> 6, lane = threadIdx.x & 63;
  const int row = blockIdx.x * 4 + wv;      // row = m*B + b
  const int m = row >> 12, b = row & 4095;
  const __bf16* r = ys + (long)row * 1024;
  float vals[16]; int cnt = 0; float mx = -3.4e38f;
  for (int c = lane; c < 1000; c += 64) {
    float v = (float)r[c];
    vals[cnt++] = v;
    mx = fmaxf(mx, v);
  }
  #pragma unroll
  for (int o = 32; o >= 1; o >>= 1) mx = fmaxf(mx, __shfl_xor(mx, o));
  float s = 0.0f;
  for (int i = 0; i < cnt; ++i) s += __expf(vals[i] - mx);
  #pragma unroll
  for (int o = 32; o >= 1; o >>= 1) s += __shfl_xor(s, o);
  if (lane == 0) offv[(long)b * 16 + m] = logp[(long)b * 16 + m] - mx - logf(s);
}

// ---------------- final mixture: y[b][c] = logsumexp_m(ys[m][b][c] + off[b][m]) ----------------
__global__ __launch_bounds__(256)
void final_mix_kernel(const __bf16* __restrict__ ys,  // [16][B][1024]
                      const float* __restrict__ offv, // [B][16]
                      float* __restrict__ y,          // [B][1000] (d_out)
                      int B)
{
  const int b = blockIdx.x;
  __shared__ float so[16];
  if (threadIdx.x < 16) so[threadIdx.x] = offv[(long)b * 16 + threadIdx.x];
  __syncthreads();
  for (int c = threadIdx.x; c < 1000; c += 256) {
    float vals[16], mx = -3.4e38f;
    #pragma unroll
    for (int m = 0; m < 16; ++m) {
      float v = (float)ys[((long)m * B + b) * 1024 + c] + so[m];
      vals[m] = v;
      mx = fmaxf(mx, v);
    }
    float s = 0.0f;
    #pragma unroll
    for (int m = 0; m < 16; ++m) s += __expf(vals[m] - mx);
    y[(long)b * 1000 + c] = mx + logf(s);
  }
}

extern "C" void kernel_launch(void* const* d_in, const int* in_sizes, int n_in,
                              void* d_out, int out_size, void* d_ws, size_t ws_size,
                              hipStream_t stream) {
  (void)in_sizes; (void)n_in; (void)out_size; (void)ws_size;
  const float* x  = (const float*)d_in[0];
  const float* W1 = (const float*)d_in[1];
  const float* b1 = (const float*)d_in[2];
  const float* W2 = (const float*)d_in[3];
  const float* b2 = (const float*)d_in[4];
  const float* Wo = (const float*)d_in[5];
  const float* bo = (const float*)d_in[6];
  const float* Wd = (const float*)d_in[7];
  const float* bd = (const float*)d_in[8];
  float* out = (float*)d_out;

  const int B = 4096, DIN = 1024, H = 2048, C = 1000, Cp = 1024, M = 16;

  char* ws = (char*)d_ws;
  // persistent layout
  size_t off_h2  = 0;                                      // [16][B][H] bf16   268 MB
  size_t off_ys  = off_h2  + (size_t)M * B * H * 2;        // [16][B][Cp] bf16  134 MB
  size_t off_woT = off_ys  + (size_t)M * B * Cp * 2;       // [16][Cp][H] bf16   67 MB
  size_t off_xb  = off_woT + (size_t)M * Cp * H * 2;       // [B][DIN] bf16     8.4 MB
  size_t off_dm  = off_xb  + (size_t)B * DIN * 2;          // [B][16][16] f32     4 MB
  size_t off_lp  = off_dm  + (size_t)B * M * M * 4;        // [B][16] f32
  size_t off_off = off_lp  + (size_t)B * M * 4;            // [B][16] f32
  // chunk scratch (4 experts), aliased over [off_ys, off_ys+201MB): dead before ys/woT written
  size_t cs_w1t = off_ys;                                  // 4*[H][DIN] bf16  16.8 MB
  size_t cs_w2t = cs_w1t + (size_t)4 * H * DIN * 2;        // 4*[H][H]  bf16   33.6 MB
  size_t cs_h1  = cs_w2t + (size_t)4 * H * H * 2;          // 4*[B][H]  bf16   67.1 MB

  __bf16* h2  = (__bf16*)(ws + off_h2);
  __bf16* ys  = (__bf16*)(ws + off_ys);
  __bf16* woT = (__bf16*)(ws + off_woT);
  __bf16* xb  = (__bf16*)(ws + off_xb);
  float*  Dm  = (float*)(ws + off_dm);
  float*  lp  = (float*)(ws + off_lp);
  float*  ofv = (float*)(ws + off_off);
  __bf16* w1t = (__bf16*)(ws + cs_w1t);
  __bf16* w2t = (__bf16*)(ws + cs_w2t);
  __bf16* h1g = (__bf16*)(ws + cs_h1);

  // 1. x -> bf16
  cvt_f32_bf16_kernel<<<dim3((B * DIN) / 1024), 256, 0, stream>>>(x, xb, (long)B * DIN);

  // 2. expert chunks of 4: W1^T, GEMM1(relu), W2^T, GEMM2(relu) -> h2
  for (int g = 0; g < 4; ++g) {
    transpose_cvt_kernel<<<dim3(DIN / 32, H / 32, 4), dim3(32, 8, 1), 0, stream>>>(
        W1 + (long)4 * g * DIN * H, w1t, DIN, H, H, (long)DIN * H, (long)H * DIN);
    gemm_bt<1><<<dim3(B / 128, H / 128, 4), 256, 0, stream>>>(
        xb, w1t, b1 + (long)4 * g * H, h1g, B, H, DIN, H,
        0L, (long)H * DIN, (long)H, (long)B * H);
    transpose_cvt_kernel<<<dim3(H / 32, H / 32, 4), dim3(32, 8, 1), 0, stream>>>(
        W2 + (long)4 * g * H * H, w2t, H, H, H, (long)H * H, (long)H * H);
    gemm_bt<1><<<dim3(B / 128, H / 128, 4), 256, 0, stream>>>(
        h1g, w2t, b2 + (long)4 * g * H, h2 + (long)4 * g * B * H, B, H, H, H,
        (long)B * H, (long)H * H, (long)H, (long)B * H);
  }

  // 3. Wo^T (pad 1000->1024 with zeros), batched GEMM3 -> ys
  transpose_cvt_kernel<<<dim3(H / 32, Cp / 32, M), dim3(32, 8, 1), 0, stream>>>(
      Wo, woT, H, C, Cp, (long)H * C, (long)Cp * H);
  gemm_bt<0><<<dim3(B / 128, Cp / 128, M), 256, 0, stream>>>(
      h2, woT, bo, ys, B, Cp, H, C,
      (long)B * H, (long)Cp * H, (long)C, (long)B * Cp);

  // 4. delegation logits + softmax
  delegation_kernel<<<dim3(B, M), 64, 0, stream>>>(h2, Wd, bd, Dm, B);

  // 5. power iteration -> power output + log p
  power_kernel<<<dim3(B / 4), 256, 0, stream>>>(Dm, out + (long)B * C, lp, B);

  // 6. row stats (max/lse) folded with log p
  rowstats_kernel<<<dim3(M * B / 4), 256, 0, stream>>>(ys, lp, ofv, B);

  // 7. final logsumexp over experts -> y
  final_mix_kernel<<<dim3(B), 256, 0, stream>>>(ys, ofv, out, B);
}